// Round 10
// baseline (178.723 us; speedup 1.0000x reference)
//
#include <hip/hip_runtime.h>
#include <math.h>

// Problem constants (setup_inputs: S=2048, U=10, D=256)
#define SS   2048
#define UU   10
#define DD   256
#define BB   (SS * UU)   // 20480 rows
#define EPSF 1e-8f

typedef __attribute__((ext_vector_type(8))) short   bf16x8;
typedef __attribute__((ext_vector_type(4))) float   floatx4;

__device__ static inline unsigned short f2bf(float f) {
    union { float f; unsigned u; } v; v.f = f;
    unsigned r = (v.u + 0x7FFFu + ((v.u >> 16) & 1u)) >> 16;  // RNE
    return (unsigned short)r;
}

__device__ static inline void gl_lds16(const unsigned short* g, unsigned short* l) {
    // 16B per lane; LDS dest = wave-uniform base + lane*16
    __builtin_amdgcn_global_load_lds((const __attribute__((address_space(1))) void*)g,
                                     (__attribute__((address_space(3))) void*)l, 16, 0, 0);
}

// ---- Kernel 1 (prep, R8 version): normalize rows -> Enb, centroid+normalize
//      -> Cnb, zero sumexp/out/done. One wave owns 2 full speakers; 20
//      independent 16B loads/lane in flight; interleaved shuffle reductions. ----
__global__ __launch_bounds__(256) void prep_kernel(const float* __restrict__ E,
                                                   unsigned short* __restrict__ Enb,
                                                   unsigned short* __restrict__ Cnb,
                                                   float* __restrict__ sumexp,
                                                   unsigned int* __restrict__ done,
                                                   float* __restrict__ out) {
    const int wid = threadIdx.x >> 6, lane = threadIdx.x & 63;

    if (threadIdx.x < 80) sumexp[blockIdx.x * 80 + threadIdx.x] = 0.f;
    if (blockIdx.x == 0) {
        if (threadIdx.x < 160) done[threadIdx.x] = 0u;   // BB/128 = 160 counters
        if (threadIdx.x == 0) out[0] = 0.f;
    }

#pragma unroll
    for (int sp2 = 0; sp2 < 2; ++sp2) {
        const int sp = blockIdx.x * 8 + wid * 2 + sp2;   // speaker id
        const float* rb = E + (size_t)sp * UU * DD + lane * 4;

        float4 v[UU];
#pragma unroll
        for (int u = 0; u < UU; ++u) v[u] = *(const float4*)(rb + u * DD);

        float ssq[UU];
#pragma unroll
        for (int u = 0; u < UU; ++u)
            ssq[u] = v[u].x * v[u].x + v[u].y * v[u].y + v[u].z * v[u].z + v[u].w * v[u].w;
#pragma unroll
        for (int off = 32; off; off >>= 1) {
#pragma unroll
            for (int u = 0; u < UU; ++u) ssq[u] += __shfl_xor(ssq[u], off, 64);
        }

        unsigned short* eb = Enb + (size_t)sp * UU * DD + lane * 4;
        float cx = 0.f, cy = 0.f, cz = 0.f, cw = 0.f;
#pragma unroll
        for (int u = 0; u < UU; ++u) {
            const float rinv = 1.0f / fmaxf(sqrtf(ssq[u]), EPSF);
            ushort4 o;
            o.x = f2bf(v[u].x * rinv); o.y = f2bf(v[u].y * rinv);
            o.z = f2bf(v[u].z * rinv); o.w = f2bf(v[u].w * rinv);
            *(ushort4*)(eb + u * DD) = o;
            cx += v[u].x; cy += v[u].y; cz += v[u].z; cw += v[u].w;
        }

        cx *= 0.1f; cy *= 0.1f; cz *= 0.1f; cw *= 0.1f;
        float cs = cx * cx + cy * cy + cz * cz + cw * cw;
#pragma unroll
        for (int off = 32; off; off >>= 1) cs += __shfl_xor(cs, off, 64);
        const float rinv = 1.0f / fmaxf(sqrtf(cs), EPSF);
        ushort4 oc;
        oc.x = f2bf(cx * rinv); oc.y = f2bf(cy * rinv);
        oc.z = f2bf(cz * rinv); oc.w = f2bf(cw * rinv);
        *(ushort4*)(Cnb + (size_t)sp * DD + lane * 4) = oc;
    }
}

// ---- Kernel 2: bf16 MFMA GEMM (Enb x Cnb^T) fused with exp-sum + pos AND
//      (new) fused finalize. R8 core verbatim (measured best 45.3us class):
//      128x128 tile, 2x2 waves, 4x4 16x16x32 tiles, BK=32 single-buffered
//      2-barrier step, swizzled LDS granules, NBN=2 panel loop, cross-panel
//      rs accumulator, bijective XCD swizzle.
// NEW: last-block-done finalize. Each bm row-group is written by exactly 8
// blocks (16 panels / NBN). After sumexp atomics: threadfence + ticket
// atomicAdd(done[bm]); the 8th block re-reads sumexp/posArr via
// atomicAdd(p, 0.0f) (device-scope coherent read; immune to XCD-L2 staleness,
// G16), computes log(sumexp)-pos for its 128 rows, block-reduces, and
// atomically adds the partial mean to out. No spin-waits -> no deadlock.
#define BM  128
#define BN  128
#define BK  32
#define NBN 2            // bn panels per block; grid = 160 * (16/NBN) = 1280

__device__ __forceinline__ void chunk_mfma(const unsigned short* Ab,
                                           const unsigned short* Bb,
                                           const int* aoff, const int* boff,
                                           floatx4 (&acc)[4][4]) {
    bf16x8 af[4], bfr[4];
#pragma unroll
    for (int t = 0; t < 4; ++t) af[t]  = *(const bf16x8*)(Ab + aoff[t]);
#pragma unroll
    for (int t = 0; t < 4; ++t) bfr[t] = *(const bf16x8*)(Bb + boff[t]);
#pragma unroll
    for (int mt = 0; mt < 4; ++mt)
#pragma unroll
        for (int nt = 0; nt < 4; ++nt)
            acc[mt][nt] = __builtin_amdgcn_mfma_f32_16x16x32_bf16(af[mt], bfr[nt], acc[mt][nt], 0, 0, 0);
}

__global__ __launch_bounds__(256) void gemm_lse_kernel(const unsigned short* __restrict__ Enb,
                                                       const unsigned short* __restrict__ Cnb,
                                                       float* __restrict__ posArr,
                                                       float* __restrict__ sumexp,
                                                       unsigned int* __restrict__ done,
                                                       float* __restrict__ out) {
    __shared__ unsigned short As[BM * BK];   // 8 KB, single-buffered
    __shared__ unsigned short Bs[BN * BK];   // 8 KB
    __shared__ float pr[4];
    __shared__ unsigned int oldc;

    const int tid  = threadIdx.x;
    const int wid  = tid >> 6, lane = tid & 63;
    const int l15  = lane & 15, quad = lane >> 4;
    const int wave_m = wid >> 1, wave_n = wid & 1;

    // bijective XCD swizzle: grid 1280 = 8 XCDs x 160. Within an XCD, 8
    // consecutive swz share bm -> one A-panel per XCD L2, reused 8x.
    const int swz = (blockIdx.x & 7) * 160 + (blockIdx.x >> 3);
    const int bm  = swz >> 3;                 // 0..159
    const int bnb = (swz & 7) * NBN;          // panel group base
    const int row0 = bm * BM;

    // staging map: 16 sub-chunks of 1 KB (16 rows x 32k); A: c=0..7, B:
    // c=8..15; 4 per wave. lane -> row rl=lane>>2, slot sl=lane&3; fetch
    // logical granule sl^((rl>>1)&3) (pre-swizzled global source, linear LDS
    // dest -> consistent with the fragment-read swizzle).
    const int rl = lane >> 2;
    const int gf = ((lane & 3) ^ ((rl >> 1) & 3)) * 8;
    const unsigned short* gpA[4];
    unsigned short* lp[4];
    size_t goffB[4];
#pragma unroll
    for (int i = 0; i < 4; ++i) {
        const int c = wid * 4 + i;
        if (c < 8) {
            gpA[i]  = Enb + (size_t)(row0 + c * 16 + rl) * DD + gf;
            lp[i]   = As + c * 512;
            goffB[i] = 0;
        } else {
            gpA[i]  = nullptr;
            lp[i]   = Bs + (c - 8) * 512;
            goffB[i] = (size_t)((c - 8) * 16 + rl) * DD + gf;
        }
    }

    // fragment offsets: row r = wtile*16 + l15, elem = r*BK + (quad^((l15>>1)&3))*8
    const int fswz = (quad ^ ((l15 >> 1) & 3)) * 8;
    int aoff[4], boff[4];
#pragma unroll
    for (int t = 0; t < 4; ++t) {
        aoff[t] = (wave_m * 64 + t * 16 + l15) * BK + fswz;
        boff[t] = (wave_n * 64 + t * 16 + l15) * BK + fswz;
    }

    // hoisted labels + cross-panel exp accumulators
    int lbl[4][4];
    float rs[4][4];
#pragma unroll
    for (int mt = 0; mt < 4; ++mt) {
        const int growb = row0 + wave_m * 64 + mt * 16 + quad * 4;
#pragma unroll
        for (int r = 0; r < 4; ++r) {
            lbl[mt][r] = (growb + r) / UU;
            rs[mt][r]  = 0.f;
        }
    }

    floatx4 acc[4][4];

#pragma unroll
    for (int bl = 0; bl < NBN; ++bl) {
        const int n0 = (bnb + bl) * BN;
        const unsigned short* gp[4];
#pragma unroll
        for (int i = 0; i < 4; ++i) {
            const int c = wid * 4 + i;
            gp[i] = (c < 8) ? gpA[i] : (Cnb + (size_t)n0 * DD + goffB[i]);
        }

#pragma unroll
        for (int i = 0; i < 4; ++i)
#pragma unroll
            for (int j = 0; j < 4; ++j) acc[i][j] = (floatx4){0.f, 0.f, 0.f, 0.f};

        // R0/R3 K-loop verbatim: sync; stage; sync; compute
        for (int k0 = 0; k0 < DD; k0 += BK) {
            __syncthreads();                      // prior LDS reads done
#pragma unroll
            for (int i = 0; i < 4; ++i) gl_lds16(gp[i] + k0, lp[i]);
            __syncthreads();                      // vmcnt drained: tiles landed
            chunk_mfma(As, Bs, aoff, boff, acc);
        }

        // per-panel epilogue: exp-accumulate into cross-panel rs
#pragma unroll
        for (int mt = 0; mt < 4; ++mt) {
            const int growb = row0 + wave_m * 64 + mt * 16 + quad * 4;
#pragma unroll
            for (int nt = 0; nt < 4; ++nt) {
                const int col = n0 + wave_n * 64 + nt * 16 + l15;
#pragma unroll
                for (int r = 0; r < 4; ++r) {
                    const float sim = acc[mt][nt][r];
                    if (col == lbl[mt][r]) {
                        posArr[growb + r] = sim;     // excluded from sum
                    } else {
                        rs[mt][r] += __expf(sim);
                    }
                }
            }
        }
    }

    // once-per-block reduce + atomics (C/D layout: col=l15, row=quad*4+reg)
#pragma unroll
    for (int mt = 0; mt < 4; ++mt) {
        const int growb = row0 + wave_m * 64 + mt * 16 + quad * 4;
#pragma unroll
        for (int m = 1; m < 16; m <<= 1) {
#pragma unroll
            for (int r = 0; r < 4; ++r) rs[mt][r] += __shfl_xor(rs[mt][r], m, 64);
        }
        if (l15 == 0) {
#pragma unroll
            for (int r = 0; r < 4; ++r) atomicAdd(&sumexp[growb + r], rs[mt][r]);
        }
    }

    // ---- fused finalize: canonical threadfence + ticket pattern ----
    __threadfence();                         // my sumexp/posArr writes visible
    __syncthreads();                         // all waves of this block done
    if (tid == 0) oldc = atomicAdd(&done[bm], 1u);
    __syncthreads();
    if (oldc == 7u) {                        // last of the 8 blocks for this bm
        float val = 0.f;
        if (tid < BM) {
            const int r = row0 + tid;
            const float se = atomicAdd(&sumexp[r], 0.0f);   // coherent read
            const float pv = atomicAdd(&posArr[r], 0.0f);   // coherent read
            val = logf(se) - pv;
        }
#pragma unroll
        for (int off = 32; off; off >>= 1) val += __shfl_xor(val, off, 64);
        if (lane == 0) pr[wid] = val;
        __syncthreads();
        if (tid == 0)
            atomicAdd(out, (pr[0] + pr[1] + pr[2] + pr[3]) * (1.0f / (float)BB));
    }
}

extern "C" void kernel_launch(void* const* d_in, const int* in_sizes, int n_in,
                              void* d_out, int out_size, void* d_ws, size_t ws_size,
                              hipStream_t stream) {
    const float* E = (const float*)d_in[0];
    float* out = (float*)d_out;

    unsigned short* Enb = (unsigned short*)d_ws;            // BB*DD bf16 = 10.5 MB
    unsigned short* Cnb = Enb + (size_t)BB * DD;            // SS*DD bf16 = 1 MB
    float* posArr = (float*)(Cnb + (size_t)SS * DD);        // BB floats
    float* sumexp = posArr + BB;                            // BB floats (zeroed by prep)
    unsigned int* done = (unsigned int*)(sumexp + BB);      // 160 counters (zeroed by prep)

    prep_kernel<<<SS / 8, 256, 0, stream>>>(E, Enb, Cnb, sumexp, done, out);
    gemm_lse_kernel<<<(BB / BM) * (SS / BN / NBN), 256, 0, stream>>>(Enb, Cnb, posArr, sumexp, done, out);
}

// Round 11
// 120.230 us; speedup vs baseline: 1.4865x; 1.4865x over previous
//
#include <hip/hip_runtime.h>
#include <math.h>

// Problem constants (setup_inputs: S=2048, U=10, D=256)
#define SS   2048
#define UU   10
#define DD   256
#define BB   (SS * UU)   // 20480 rows
#define EPSF 1e-8f

typedef __attribute__((ext_vector_type(8))) short   bf16x8;
typedef __attribute__((ext_vector_type(4))) float   floatx4;

__device__ static inline unsigned short f2bf(float f) {
    union { float f; unsigned u; } v; v.f = f;
    unsigned r = (v.u + 0x7FFFu + ((v.u >> 16) & 1u)) >> 16;  // RNE
    return (unsigned short)r;
}

__device__ static inline void gl_lds16(const unsigned short* g, unsigned short* l) {
    // 16B per lane; LDS dest = wave-uniform base + lane*16
    __builtin_amdgcn_global_load_lds((const __attribute__((address_space(1))) void*)g,
                                     (__attribute__((address_space(3))) void*)l, 16, 0, 0);
}

// ---- Kernel 1 (prep, R8 version): normalize rows -> Enb, centroid+normalize
//      -> Cnb, zero sumexp/out. One wave owns 2 full speakers; 20 independent
//      16B loads/lane in flight; interleaved shuffle reductions. ----
__global__ __launch_bounds__(256) void prep_kernel(const float* __restrict__ E,
                                                   unsigned short* __restrict__ Enb,
                                                   unsigned short* __restrict__ Cnb,
                                                   float* __restrict__ sumexp,
                                                   float* __restrict__ out) {
    const int wid = threadIdx.x >> 6, lane = threadIdx.x & 63;

    if (threadIdx.x < 80) sumexp[blockIdx.x * 80 + threadIdx.x] = 0.f;
    if (blockIdx.x == 0 && threadIdx.x == 0) out[0] = 0.f;

#pragma unroll
    for (int sp2 = 0; sp2 < 2; ++sp2) {
        const int sp = blockIdx.x * 8 + wid * 2 + sp2;   // speaker id
        const float* rb = E + (size_t)sp * UU * DD + lane * 4;

        float4 v[UU];
#pragma unroll
        for (int u = 0; u < UU; ++u) v[u] = *(const float4*)(rb + u * DD);

        float ssq[UU];
#pragma unroll
        for (int u = 0; u < UU; ++u)
            ssq[u] = v[u].x * v[u].x + v[u].y * v[u].y + v[u].z * v[u].z + v[u].w * v[u].w;
#pragma unroll
        for (int off = 32; off; off >>= 1) {
#pragma unroll
            for (int u = 0; u < UU; ++u) ssq[u] += __shfl_xor(ssq[u], off, 64);
        }

        unsigned short* eb = Enb + (size_t)sp * UU * DD + lane * 4;
        float cx = 0.f, cy = 0.f, cz = 0.f, cw = 0.f;
#pragma unroll
        for (int u = 0; u < UU; ++u) {
            const float rinv = 1.0f / fmaxf(sqrtf(ssq[u]), EPSF);
            ushort4 o;
            o.x = f2bf(v[u].x * rinv); o.y = f2bf(v[u].y * rinv);
            o.z = f2bf(v[u].z * rinv); o.w = f2bf(v[u].w * rinv);
            *(ushort4*)(eb + u * DD) = o;
            cx += v[u].x; cy += v[u].y; cz += v[u].z; cw += v[u].w;
        }

        cx *= 0.1f; cy *= 0.1f; cz *= 0.1f; cw *= 0.1f;
        float cs = cx * cx + cy * cy + cz * cz + cw * cw;
#pragma unroll
        for (int off = 32; off; off >>= 1) cs += __shfl_xor(cs, off, 64);
        const float rinv = 1.0f / fmaxf(sqrtf(cs), EPSF);
        ushort4 oc;
        oc.x = f2bf(cx * rinv); oc.y = f2bf(cy * rinv);
        oc.z = f2bf(cz * rinv); oc.w = f2bf(cw * rinv);
        *(ushort4*)(Cnb + (size_t)sp * DD + lane * 4) = oc;
    }
}

// ---- Kernel 2: bf16 MFMA GEMM (Enb x Cnb^T) fused with exp-sum + pos ----
// Round-11: R0 core with BK=64 — the drain-count discriminator. Same 328 MB
// staged, same verified 16-row/32-k sub-chunk layout (just TWO chunks per
// operand per drain), same TLP class (32 KB LDS, ~2+ blocks/CU), but HALF
// the barrier-drain pairs (4/block of 32 KB vs 8 of 16 KB). R10's fused
// finalize REVERTED (device-scope threadfence = repeated cross-XCD L2
// writeback, gemm 45->113 us measured). Standalone finalize restored.
#define BM  128
#define BN  128
#define BK  64           // two 32-k chunks per drain
#define CHK 32           // chunk K-width (row stride in shorts, verified layout)

__device__ __forceinline__ void chunk_mfma(const unsigned short* Ab,
                                           const unsigned short* Bb,
                                           const int* aoff, const int* boff,
                                           floatx4 (&acc)[4][4]) {
    bf16x8 af[4], bfr[4];
#pragma unroll
    for (int t = 0; t < 4; ++t) af[t]  = *(const bf16x8*)(Ab + aoff[t]);
#pragma unroll
    for (int t = 0; t < 4; ++t) bfr[t] = *(const bf16x8*)(Bb + boff[t]);
#pragma unroll
    for (int mt = 0; mt < 4; ++mt)
#pragma unroll
        for (int nt = 0; nt < 4; ++nt)
            acc[mt][nt] = __builtin_amdgcn_mfma_f32_16x16x32_bf16(af[mt], bfr[nt], acc[mt][nt], 0, 0, 0);
}

__global__ __launch_bounds__(256) void gemm_lse_kernel(const unsigned short* __restrict__ Enb,
                                                       const unsigned short* __restrict__ Cnb,
                                                       float* __restrict__ posArr,
                                                       float* __restrict__ sumexp) {
    __shared__ unsigned short As[2 * BM * CHK];   // 16 KB: k-half h at As + h*4096
    __shared__ unsigned short Bs[2 * BN * CHK];   // 16 KB

    const int tid  = threadIdx.x;
    const int wid  = tid >> 6, lane = tid & 63;
    const int l15  = lane & 15, quad = lane >> 4;
    const int wave_m = wid >> 1, wave_n = wid & 1;

    // XCD-bijective swizzle: grid 2560 = 8 XCDs x 320; within an XCD, bn runs
    // fastest -> one A-panel per XCD L2 (FETCH 41.5 -> 9.3 MB, measured R1).
    const int swz = (blockIdx.x & 7) * 320 + (blockIdx.x >> 3);
    const int bn = swz & 15;                 // SS/BN = 16
    const int bm = swz >> 4;                 // BB/BM = 160
    const int row0 = bm * BM, n0 = bn * BN;

    // staging map (verified R0 sub-chunk, duplicated per k-half):
    // 32 sub-chunks of 1 KB (16 rows x 32k). c = wid*8+i; op=c>>4 (A/B),
    // kh=(c>>3)&1 (k-half), sub=c&7 (row group). lane -> row rl=lane>>2,
    // slot sl=lane&3; fetch logical granule sl^((rl>>1)&3) (pre-swizzled
    // global source, linear LDS dest -> consistent with fragment-read swizzle).
    const int rl = lane >> 2;
    const int gf = ((lane & 3) ^ ((rl >> 1) & 3)) * 8;
    const unsigned short* gp[8];
    unsigned short* lp[8];
#pragma unroll
    for (int i = 0; i < 8; ++i) {
        const int c   = wid * 8 + i;
        const int op  = c >> 4;
        const int kh  = (c >> 3) & 1;
        const int sub = c & 7;
        if (op == 0) {
            gp[i] = Enb + (size_t)(row0 + sub * 16 + rl) * DD + kh * CHK + gf;
            lp[i] = As + kh * (BM * CHK) + sub * 512;
        } else {
            gp[i] = Cnb + (size_t)(n0 + sub * 16 + rl) * DD + kh * CHK + gf;
            lp[i] = Bs + kh * (BN * CHK) + sub * 512;
        }
    }

    // fragment offsets (within a 32-k chunk): row r = wtile*16 + l15,
    // elem = r*CHK + (quad^((l15>>1)&3))*8  -- verified conflict-free
    const int fswz = (quad ^ ((l15 >> 1) & 3)) * 8;
    int aoff[4], boff[4];
#pragma unroll
    for (int t = 0; t < 4; ++t) {
        aoff[t] = (wave_m * 64 + t * 16 + l15) * CHK + fswz;
        boff[t] = (wave_n * 64 + t * 16 + l15) * CHK + fswz;
    }

    floatx4 acc[4][4];
#pragma unroll
    for (int i = 0; i < 4; ++i)
#pragma unroll
        for (int j = 0; j < 4; ++j) acc[i][j] = (floatx4){0.f, 0.f, 0.f, 0.f};

    // K-loop: 4 drains of 32 KB (vs R0's 8 of 16 KB), 2-barrier step verbatim
    for (int k0 = 0; k0 < DD; k0 += BK) {
        __syncthreads();                      // prior LDS reads done
#pragma unroll
        for (int i = 0; i < 8; ++i) gl_lds16(gp[i] + k0, lp[i]);
        __syncthreads();                      // vmcnt drained: both chunks landed
        chunk_mfma(As, Bs, aoff, boff, acc);
        chunk_mfma(As + BM * CHK, Bs + BN * CHK, aoff, boff, acc);
    }

    // epilogue: C/D layout col=l15 (n), row=quad*4+reg (m) -- R0 verbatim
#pragma unroll
    for (int mt = 0; mt < 4; ++mt) {
        float rs[4] = {0.f, 0.f, 0.f, 0.f};
        const int growb = row0 + wave_m * 64 + mt * 16 + quad * 4;
#pragma unroll
        for (int nt = 0; nt < 4; ++nt) {
            const int col = n0 + wave_n * 64 + nt * 16 + l15;
#pragma unroll
            for (int r = 0; r < 4; ++r) {
                const int grow = growb + r;
                const float sim = acc[mt][nt][r];
                if (col == grow / UU) {
                    posArr[grow] = sim;           // excluded from sum (-inf mask)
                } else {
                    rs[r] += __expf(sim);
                }
            }
        }
#pragma unroll
        for (int m = 1; m < 16; m <<= 1) {
#pragma unroll
            for (int r = 0; r < 4; ++r) rs[r] += __shfl_xor(rs[r], m, 64);
        }
        if (l15 == 0) {
#pragma unroll
            for (int r = 0; r < 4; ++r) atomicAdd(&sumexp[growb + r], rs[r]);
        }
    }
}

// ---- Kernel 3: single-pass finalize: mean of (-pos + log(sumexp)) ----
__global__ __launch_bounds__(256) void finalize_kernel(const float* __restrict__ posArr,
                                                       const float* __restrict__ sumexp,
                                                       float* __restrict__ out) {
    __shared__ float sred[256];
    const int tid = threadIdx.x;
    const int r = blockIdx.x * 256 + tid;
    sred[tid] = logf(sumexp[r]) - posArr[r];
    __syncthreads();
#pragma unroll
    for (int off = 128; off; off >>= 1) {
        if (tid < off) sred[tid] += sred[tid + off];
        __syncthreads();
    }
    if (tid == 0) atomicAdd(out, sred[0] * (1.0f / (float)BB));
}

extern "C" void kernel_launch(void* const* d_in, const int* in_sizes, int n_in,
                              void* d_out, int out_size, void* d_ws, size_t ws_size,
                              hipStream_t stream) {
    const float* E = (const float*)d_in[0];
    float* out = (float*)d_out;

    unsigned short* Enb = (unsigned short*)d_ws;            // BB*DD bf16 = 10.5 MB
    unsigned short* Cnb = Enb + (size_t)BB * DD;            // SS*DD bf16 = 1 MB
    float* posArr = (float*)(Cnb + (size_t)SS * DD);        // BB floats
    float* sumexp = posArr + BB;                            // BB floats (zeroed by prep)

    prep_kernel<<<SS / 8, 256, 0, stream>>>(E, Enb, Cnb, sumexp, out);
    gemm_lse_kernel<<<(BB / BM) * (SS / BN), 256, 0, stream>>>(Enb, Cnb, posArr, sumexp);
    finalize_kernel<<<BB / 256, 256, 0, stream>>>(posArr, sumexp, out);
}